// Round 8
// baseline (215.116 us; speedup 1.0000x reference)
//
#include <hip/hip_runtime.h>
#include <hip/hip_bf16.h>

typedef __bf16 bf16x8 __attribute__((ext_vector_type(8)));
typedef short short8 __attribute__((ext_vector_type(8)));
typedef float f32x4 __attribute__((ext_vector_type(4)));
typedef unsigned short ushort_t;

#define T_LEN 32768
#define B_SZ 4
#define NSLOW 2047
#define NSEQ (B_SZ * NSLOW)   // 8188
#define GH 64
#define G3 192
#define NL 4
#define HID 32
#define NCH 256               // fast-path chunks per batch (len 128)
#define L2E 1.44269504088896341f

// staging-buffer (bf16) element offsets, concatenated in input order
#define OFF_X    0
#define OFF_FCW  131072
#define OFF_FCB  131136
#define OFF_WIH  131200
#define OFF_WHH  180352
#define OFF_BIH  229504
#define OFF_BHH  230272
#define OFF_OFW  231040
#define OFF_OFB  235136
#define OFF_FINW 235200
#define OFF_FINB 235232
#define OFF_FOW  235264
#define OFF_FOB  235296
#define CONV_TOTAL 235297
#define CONV_PAD_BYTES 470656   // 16B-aligned end of staging region

static __device__ __forceinline__ float bf2f(ushort_t u) {
    union { unsigned u; float f; } c; c.u = ((unsigned)u) << 16; return c.f;
}
static __device__ __forceinline__ ushort_t f2bf(float f) {
    union { float f; unsigned u; } c; c.f = f;
    unsigned r = (c.u + 0x7FFFu + ((c.u >> 16) & 1u)) >> 16;
    return (ushort_t)r;
}
static __device__ __forceinline__ unsigned pk2bf(float a, float b) {
    float2 f; f.x = a; f.y = b;
    __hip_bfloat162 h = __float22bfloat162_rn(f);   // v_cvt_pk_bf16_f32
    unsigned u;
    __builtin_memcpy(&u, &h, 4);
    return u;
}
static __device__ __forceinline__ f32x4 mfma16(short8 a, short8 b, f32x4 c) {
    return __builtin_amdgcn_mfma_f32_16x16x32_bf16(
        __builtin_bit_cast(bf16x8, a), __builtin_bit_cast(bf16x8, b), c, 0, 0, 0);
}
// LDS layout: short off = ((t*8 + kb)*16 + (seq ^ (kb&7)))*8 + i
static __device__ __forceinline__ int xoff(int t, int kb, int seq) {
    return ((((t << 3) + kb) << 4) + (seq ^ (kb & 7))) << 3;
}
static __device__ __forceinline__ short8 load_frag_scaled(const ushort_t* p, float s) {
    uint4 r = *(const uint4*)p;
    unsigned aa[4] = {r.x, r.y, r.z, r.w};
    short8 o;
#pragma unroll
    for (int i = 0; i < 4; ++i) {
        o[2 * i]     = (short)f2bf(bf2f((ushort_t)(aa[i] & 0xffffu)) * s);
        o[2 * i + 1] = (short)f2bf(bf2f((ushort_t)(aa[i] >> 16)) * s);
    }
    return o;
}

// ---------------- K0: stage all inputs as bf16 (self-detecting dtype) ------
struct Ptrs13 { const void* p[13]; };

__global__ __launch_bounds__(256) void convert_kernel(Ptrs13 ptrs,
                                                      int* __restrict__ flag,
                                                      ushort_t* __restrict__ dst)
{
    // per-block dtype detection on the first 256 ushorts of x
    __shared__ int scnt;
    if (threadIdx.x == 0) scnt = 0;
    __syncthreads();
    {
        ushort_t u = ((const ushort_t*)ptrs.p[0])[threadIdx.x];
        int e = (u >> 7) & 0xFF;
        int ok = (e >= 80 && e <= 141) ? 1 : 0;
#pragma unroll
        for (int d = 1; d < 64; d <<= 1) ok += __shfl_xor(ok, d, 64);
        if ((threadIdx.x & 63) == 0) atomicAdd(&scnt, ok);
    }
    __syncthreads();
    const bool isbf = (scnt >= 224);   // bf16 data: ~256/256 sane exponents
    if (blockIdx.x == 0 && threadIdx.x == 0) *flag = isbf ? 1 : 0;

    const int offs[14] = {OFF_X, OFF_FCW, OFF_FCB, OFF_WIH, OFF_WHH, OFF_BIH,
                          OFF_BHH, OFF_OFW, OFF_OFB, OFF_FINW, OFF_FINB,
                          OFF_FOW, OFF_FOB, CONV_TOTAL};
    for (int idx = blockIdx.x * 256 + threadIdx.x; idx < CONV_TOTAL;
         idx += gridDim.x * 256) {
        int s = 0;
#pragma unroll
        for (int j = 1; j < 13; ++j) if (idx >= offs[j]) s = j;
        int k = idx - offs[s];
        ushort_t v = isbf ? ((const ushort_t*)ptrs.p[s])[k]
                          : f2bf(((const float*)ptrs.p[s])[k]);
        dst[idx] = v;
    }
}

// ---------------- K1: fused 4-layer GRU + out-FC + sigmoid ----------------
// Orientation: A=weights (m=gate-col), B=activations (n=seq).
// D[col][seq]: lane holds seq = lane&15, cols = jb + 4*quad + i.
//
// IN-WAVE DUAL-TILE (static ILP): each wave processes TWO independent
// 16-seq tiles (A: n0..n0+15 in LDS[0..64K), B: n0+16..n0+31 in
// LDS[64K..128K)) in one instruction stream. Rounds 0-6 proved the HW
// scheduler does NOT overlap two barrier-separated waves' dependency
// chains on a SIMD (wall = sum, 860 cyc/wave-step vs 400 issue, every
// TLP arrangement identical); interleaving the two chains statically
// lets the compiler fill chain-stall slots with the other tile's ops.
// Weights + biases are SHARED between tiles (same layer/cols): ~+35
// VGPR only. 128 KB LDS -> 1 block/CU, grid 256, 4 waves/CU.
__global__ __launch_bounds__(256, 1) void gru_kernel(
    const ushort_t* __restrict__ x, const ushort_t* __restrict__ fcw,
    const ushort_t* __restrict__ fcb, const ushort_t* __restrict__ wih,
    const ushort_t* __restrict__ whh, const ushort_t* __restrict__ bih,
    const ushort_t* __restrict__ bhh, const ushort_t* __restrict__ ofw,
    const ushort_t* __restrict__ ofb, float* __restrict__ Aslow,
    float* __restrict__ gslow)
{
    __shared__ short8 Xs8[8192];   // 128 KB: 2 tiles x (16 seq x 32 t x 64 f)
    short* Xs = (short*)Xs8;
    const int tid = threadIdx.x;
    const int w = tid >> 6, lane = tid & 63;
    const int q = lane >> 4, m = lane & 15;
    const int jb = w * 16;
    const int n0 = blockIdx.x * 32;

    // ---- fill layer-0 input: relu(x_s * fc_in_w + fc_in_b), both tiles ----
#pragma unroll 1
    for (int ii = 0; ii < 32; ++ii) {
        int cid = ii * 256 + tid;          // 0..8191
        int tl = cid >> 12, r = cid & 4095;
        int seq = r & 15, kb = (r >> 4) & 7, t = r >> 7;
        int n = n0 + tl * 16 + seq;
        if (n > NSEQ - 1) n = NSEQ - 1;
        int b = n / NSLOW, s = n - b * NSLOW;
        float xv = bf2f(x[b * T_LEN + s * 16 + t]);
        short8 v;
#pragma unroll
        for (int i = 0; i < 8; ++i) {
            int g = kb * 8 + i;
            float h = fmaf(xv, bf2f(fcw[g]), bf2f(fcb[g]));
            h = h > 0.f ? h : 0.f;
            v[i] = (short)f2bf(h);
        }
        Xs8[(tl << 12) + (xoff(t, kb, seq) >> 3)] = v;
    }

    const int col0 = jb + 4 * q;            // this lane's 4 gate-cols
    const int kbw = (col0 >> 3);            // write feature-block
    const int wsub = (col0 & 7);            // 0 or 4
    const int kofs = q * 8;
    const int wbase0 = ((kbw << 4) + (m ^ (kbw & 7))) * 8 + wsub;
    const int iA0 = (q << 4) + (m ^ q);               // xoff(0,q,m)>>3
    const int iB0 = ((4 + q) << 4) + (m ^ ((4 + q) & 7));

    float hcA[4], hcB[4];
#pragma unroll 1
    for (int l = 0; l < NL; ++l) {
        const ushort_t* wl = wih + l * G3 * GH;
        const ushort_t* ul = whh + l * G3 * GH;
        // shared A-frags (weights): lane m = gate-col jb+m, k contiguous
        short8 wR0 = load_frag_scaled(wl + (0 * 64 + jb + m) * 64 + kofs, -L2E);
        short8 wR1 = load_frag_scaled(wl + (0 * 64 + jb + m) * 64 + 32 + kofs, -L2E);
        short8 wZ0 = load_frag_scaled(wl + (1 * 64 + jb + m) * 64 + kofs, -L2E);
        short8 wZ1 = load_frag_scaled(wl + (1 * 64 + jb + m) * 64 + 32 + kofs, -L2E);
        short8 wN0 = load_frag_scaled(wl + (2 * 64 + jb + m) * 64 + kofs, 2.f * L2E);
        short8 wN1 = load_frag_scaled(wl + (2 * 64 + jb + m) * 64 + 32 + kofs, 2.f * L2E);
        short8 uR0 = load_frag_scaled(ul + (0 * 64 + jb + m) * 64 + kofs, -L2E);
        short8 uR1 = load_frag_scaled(ul + (0 * 64 + jb + m) * 64 + 32 + kofs, -L2E);
        short8 uZ0 = load_frag_scaled(ul + (1 * 64 + jb + m) * 64 + kofs, -L2E);
        short8 uZ1 = load_frag_scaled(ul + (1 * 64 + jb + m) * 64 + 32 + kofs, -L2E);
        short8 uN0 = load_frag_scaled(ul + (2 * 64 + jb + m) * 64 + kofs, 2.f * L2E);
        short8 uN1 = load_frag_scaled(ul + (2 * 64 + jb + m) * 64 + 32 + kofs, 2.f * L2E);

        f32x4 bRv, bZv, bNXv, bNHv;   // shared biases
#pragma unroll
        for (int i = 0; i < 4; ++i) {
            int c = col0 + i;
            bRv[i]  = -L2E * (bf2f(bih[l * G3 + c]) + bf2f(bhh[l * G3 + c]));
            bZv[i]  = -L2E * (bf2f(bih[l * G3 + 64 + c]) + bf2f(bhh[l * G3 + 64 + c]));
            bNXv[i] = 2.f * L2E * bf2f(bih[l * G3 + 128 + c]);
            bNHv[i] = 2.f * L2E * bf2f(bhh[l * G3 + 128 + c]);
        }

#pragma unroll
        for (int i = 0; i < 4; ++i) { hcA[i] = 0.f; hcB[i] = 0.f; }

        __syncthreads();                    // layer input fully written
        int iA = iA0, iB = iB0;             // tile-A chains (+128/t)
        int wb = wbase0;

        // ---- t = 0 peeled: h=0, gates from xacc only (both tiles) ----
        short8 cxA0 = Xs8[iA],        cxA1 = Xs8[iB];          // A: X(0)
        short8 cxB0 = Xs8[iA + 4096], cxB1 = Xs8[iB + 4096];   // B: X(0)
        short8 nxA0 = Xs8[iA + 128],  nxA1 = Xs8[iB + 128];    // A: X(1)
        short8 nxB0 = Xs8[iA + 4224], nxB1 = Xs8[iB + 4224];   // B: X(1)
        f32x4 xRA = bRv, xZA = bZv, xNA = bNXv;
        f32x4 xRB = bRv, xZB = bZv, xNB = bNXv;
        xRA = mfma16(wR0, cxA0, xRA); xRA = mfma16(wR1, cxA1, xRA);
        xRB = mfma16(wR0, cxB0, xRB); xRB = mfma16(wR1, cxB1, xRB);
        xZA = mfma16(wZ0, cxA0, xZA); xZA = mfma16(wZ1, cxA1, xZA);
        xZB = mfma16(wZ0, cxB0, xZB); xZB = mfma16(wZ1, cxB1, xZB);
        xNA = mfma16(wN0, cxA0, xNA); xNA = mfma16(wN1, cxA1, xNA);
        xNB = mfma16(wN0, cxB0, xNB); xNB = mfma16(wN1, cxB1, xNB);
#pragma unroll
        for (int i = 0; i < 4; ++i) {
            float rA = __builtin_amdgcn_rcpf(1.f + __builtin_amdgcn_exp2f(xRA[i]));
            float rB = __builtin_amdgcn_rcpf(1.f + __builtin_amdgcn_exp2f(xRB[i]));
            float zA = __builtin_amdgcn_rcpf(1.f + __builtin_amdgcn_exp2f(xZA[i]));
            float zB = __builtin_amdgcn_rcpf(1.f + __builtin_amdgcn_exp2f(xZB[i]));
            float ypA = fmaf(rA, bNHv[i], xNA[i]);
            float ypB = fmaf(rB, bNHv[i], xNB[i]);
            float nnA = fmaf(-2.f,
                __builtin_amdgcn_rcpf(1.f + __builtin_amdgcn_exp2f(ypA)), 1.f);
            float nnB = fmaf(-2.f,
                __builtin_amdgcn_rcpf(1.f + __builtin_amdgcn_exp2f(ypB)), 1.f);
            hcA[i] = fmaf(zA, hcA[i] - nnA, nnA);
            hcB[i] = fmaf(zB, hcB[i] - nnB, nnB);
        }
        *(uint2*)(Xs + wb) =
            make_uint2(pk2bf(hcA[0], hcA[1]), pk2bf(hcA[2], hcA[3]));
        *(uint2*)(Xs + wb + 32768) =
            make_uint2(pk2bf(hcB[0], hcB[1]), pk2bf(hcB[2], hcB[3]));
        // xacc(1) in barrier shadow (both tiles)
        xRA = bRv; xZA = bZv; xNA = bNXv;
        xRB = bRv; xZB = bZv; xNB = bNXv;
        xRA = mfma16(wR0, nxA0, xRA); xRA = mfma16(wR1, nxA1, xRA);
        xRB = mfma16(wR0, nxB0, xRB); xRB = mfma16(wR1, nxB1, xRB);
        xZA = mfma16(wZ0, nxA0, xZA); xZA = mfma16(wZ1, nxA1, xZA);
        xZB = mfma16(wZ0, nxB0, xZB); xZB = mfma16(wZ1, nxB1, xZB);
        xNA = mfma16(wN0, nxA0, xNA); xNA = mfma16(wN1, nxA1, xNA);
        xNB = mfma16(wN0, nxB0, xNB); xNB = mfma16(wN1, nxB1, xNB);
        iA += 128; iB += 128; wb += 1024;

#pragma unroll 1
        for (int t = 1; t < 32; ++t) {
            __syncthreads();                // h(t-1) visible
            short8 bhA0 = Xs8[iA - 128],  bhA1 = Xs8[iB - 128];
            short8 bhB0 = Xs8[iA + 3968], bhB1 = Xs8[iB + 3968]; // -128+4096
            short8 pxA0, pxA1, pxB0, pxB1;
            if (t < 31) {                   // X(t+1), slot t+1 (untouched)
                pxA0 = Xs8[iA + 128];  pxA1 = Xs8[iB + 128];
                pxB0 = Xs8[iA + 4224]; pxB1 = Xs8[iB + 4224];
            }
            f32x4 aRA = xRA, aZA = xZA, aNHA = bNHv;
            f32x4 aRB = xRB, aZB = xZB, aNHB = bNHv;
            aRA  = mfma16(uR0, bhA0, aRA);  aRA  = mfma16(uR1, bhA1, aRA);
            aRB  = mfma16(uR0, bhB0, aRB);  aRB  = mfma16(uR1, bhB1, aRB);
            aZA  = mfma16(uZ0, bhA0, aZA);  aZA  = mfma16(uZ1, bhA1, aZA);
            aZB  = mfma16(uZ0, bhB0, aZB);  aZB  = mfma16(uZ1, bhB1, aZB);
            aNHA = mfma16(uN0, bhA0, aNHA); aNHA = mfma16(uN1, bhA1, aNHA);
            aNHB = mfma16(uN0, bhB0, aNHB); aNHB = mfma16(uN1, bhB1, aNHB);
#pragma unroll
            for (int i = 0; i < 4; ++i) {
                float rA = __builtin_amdgcn_rcpf(1.f + __builtin_amdgcn_exp2f(aRA[i]));
                float rB = __builtin_amdgcn_rcpf(1.f + __builtin_amdgcn_exp2f(aRB[i]));
                float zA = __builtin_amdgcn_rcpf(1.f + __builtin_amdgcn_exp2f(aZA[i]));
                float zB = __builtin_amdgcn_rcpf(1.f + __builtin_amdgcn_exp2f(aZB[i]));
                float ypA = fmaf(rA, aNHA[i], xNA[i]);
                float ypB = fmaf(rB, aNHB[i], xNB[i]);
                float nnA = fmaf(-2.f,
                    __builtin_amdgcn_rcpf(1.f + __builtin_amdgcn_exp2f(ypA)), 1.f);
                float nnB = fmaf(-2.f,
                    __builtin_amdgcn_rcpf(1.f + __builtin_amdgcn_exp2f(ypB)), 1.f);
                hcA[i] = fmaf(zA, hcA[i] - nnA, nnA);
                hcB[i] = fmaf(zB, hcB[i] - nnB, nnB);
            }
            *(uint2*)(Xs + wb) =
                make_uint2(pk2bf(hcA[0], hcA[1]), pk2bf(hcA[2], hcA[3]));
            *(uint2*)(Xs + wb + 32768) =
                make_uint2(pk2bf(hcB[0], hcB[1]), pk2bf(hcB[2], hcB[3]));
            if (t < 31) {                   // xacc(t+1), barrier shadow
                xRA = bRv; xZA = bZv; xNA = bNXv;
                xRB = bRv; xZB = bZv; xNB = bNXv;
                xRA = mfma16(wR0, pxA0, xRA); xRA = mfma16(wR1, pxA1, xRA);
                xRB = mfma16(wR0, pxB0, xRB); xRB = mfma16(wR1, pxB1, xRB);
                xZA = mfma16(wZ0, pxA0, xZA); xZA = mfma16(wZ1, pxA1, xZA);
                xZB = mfma16(wZ0, pxB0, xZB); xZB = mfma16(wZ1, pxB1, xZB);
                xNA = mfma16(wN0, pxA0, xNA); xNA = mfma16(wN1, pxA1, xNA);
                xNB = mfma16(wN0, pxB0, xNB); xNB = mfma16(wN1, pxB1, xNB);
            }
            iA += 128; iB += 128; wb += 1024;
        }
    }

    // ---- epilogue: eps = h_last @ out_fc_w^T + b (both tiles) ----
    __syncthreads();
    short8 aLA0 = Xs8[(31 << 7) + iA0],        aLA1 = Xs8[(31 << 7) + iB0];
    short8 aLB0 = Xs8[(31 << 7) + 4096 + iA0], aLB1 = Xs8[(31 << 7) + 4096 + iB0];
    float sc = (w < 2) ? -L2E : 1.f;
    short8 o0 = load_frag_scaled(ofw + (jb + m) * 64 + kofs, sc);
    short8 o1 = load_frag_scaled(ofw + (jb + m) * 64 + 32 + kofs, sc);
    f32x4 aEb = {bf2f(ofb[col0]) * sc, bf2f(ofb[col0 + 1]) * sc,
                 bf2f(ofb[col0 + 2]) * sc, bf2f(ofb[col0 + 3]) * sc};
    f32x4 aEA = aEb, aEB = aEb;
    aEA = mfma16(o0, aLA0, aEA); aEA = mfma16(o1, aLA1, aEA);
    aEB = mfma16(o0, aLB0, aEB); aEB = mfma16(o1, aLB1, aEB);
    int nA = n0 + m;            // pad rows land in rows < 8192: harmless
    int nB = n0 + 16 + m;
    if (w < 2) {
        f32x4 vA, vB;
#pragma unroll
        for (int i = 0; i < 4; ++i) {
            vA[i] = __builtin_amdgcn_rcpf(1.f + __builtin_amdgcn_exp2f(aEA[i]));
            vB[i] = __builtin_amdgcn_rcpf(1.f + __builtin_amdgcn_exp2f(aEB[i]));
        }
        *(f32x4*)(Aslow + nA * HID + col0) = vA;
        *(f32x4*)(Aslow + nB * HID + col0) = vB;
    } else {
        *(f32x4*)(gslow + nA * HID + (col0 - 32)) = aEA;
        *(f32x4*)(gslow + nB * HID + (col0 - 32)) = aEB;
    }
}

// ---------------- K2: per-chunk (prod A, partial sum), 256 chunks ----------
__global__ __launch_bounds__(256) void pass1_kernel(
    const ushort_t* __restrict__ x, const float* __restrict__ Aslow,
    const float* __restrict__ gslow, const ushort_t* __restrict__ finw,
    const ushort_t* __restrict__ finb, float* __restrict__ P,
    float* __restrict__ S)
{
    int gt = blockIdx.x * 256 + threadIdx.x;    // 32768 = 4b * 256c * 32h
    int h = gt & 31, c = (gt >> 5) & 255, b = gt >> 13;
    float fw = bf2f(finw[h]), fb = bf2f(finb[h]);
    float Pv = 1.f, Sv = 0.f;
    int t0 = c * 128;
#pragma unroll 1
    for (int seg = 0; seg < 8; ++seg) {
        int sidx = (t0 >> 4) + seg - 1;
        if (sidx < 0) sidx = 0;
        if (sidx > NSLOW - 1) sidx = NSLOW - 1;
        float A = Aslow[(b * NSLOW + sidx) * HID + h];
        float g = gslow[(b * NSLOW + sidx) * HID + h];
        float fwg = fw * g, fbg = fb * g;
        const uint4* px = (const uint4*)(x + b * T_LEN + t0 + seg * 16);
        uint4 ra = px[0], rb = px[1];
        unsigned xa[8] = {ra.x, ra.y, ra.z, ra.w, rb.x, rb.y, rb.z, rb.w};
#pragma unroll
        for (int j = 0; j < 8; ++j) {
            float x0 = bf2f((ushort_t)(xa[j] & 0xffffu));
            float x1 = bf2f((ushort_t)(xa[j] >> 16));
            Sv = fmaf(A, Sv, fmaf(x0, fwg, fbg));
            Sv = fmaf(A, Sv, fmaf(x1, fwg, fbg));
        }
        float A2 = A * A, A4 = A2 * A2, A8 = A4 * A4;
        Pv *= A8 * A8;
    }
    P[(b * HID + h) * NCH + c] = Pv;
    S[(b * HID + h) * NCH + c] = Sv;
}

// ---------------- K3: scan of chunk summaries ----------------
__global__ __launch_bounds__(128) void scan_kernel(
    const float* __restrict__ P, const float* __restrict__ S,
    float* __restrict__ Hpre)
{
    int tid = threadIdx.x;   // 128 = (b,h)
    const float4* p4 = (const float4*)(P + tid * NCH);
    const float4* s4 = (const float4*)(S + tid * NCH);
    float* hp = Hpre + tid * NCH;
    float hr = 0.f;
#pragma unroll 8
    for (int c = 0; c < NCH / 4; ++c) {
        float4 pv = p4[c], sv = s4[c];
        hp[4 * c + 0] = hr; hr = fmaf(pv.x, hr, sv.x);
        hp[4 * c + 1] = hr; hr = fmaf(pv.y, hr, sv.y);
        hp[4 * c + 2] = hr; hr = fmaf(pv.z, hr, sv.z);
        hp[4 * c + 3] = hr; hr = fmaf(pv.w, hr, sv.w);
    }
}

// ---------------- K4: recompute states + fused output dot ----------------
__global__ __launch_bounds__(256) void pass2_kernel(
    const ushort_t* __restrict__ x, const float* __restrict__ Aslow,
    const float* __restrict__ gslow, const float* __restrict__ Hpre,
    const ushort_t* __restrict__ finw, const ushort_t* __restrict__ finb,
    const ushort_t* __restrict__ fow, const ushort_t* __restrict__ fob,
    const int* __restrict__ flag, void* __restrict__ outv)
{
    int wv = blockIdx.x * 4 + (threadIdx.x >> 6);   // 0..511
    int lane = threadIdx.x & 63;
    int half = lane >> 5, h = lane & 31;
    int pair = wv * 2 + half;                       // 0..1023 = b*NCH + c
    int b = pair >> 8, c = pair & 255;
    const bool isbf = (*flag != 0);
    ushort_t* outb = (ushort_t*)outv;
    float* outf = (float*)outv;
    float hv = Hpre[(b * HID + h) * NCH + c];
    float fw = bf2f(finw[h]), fb = bf2f(finb[h]);
    float wo = bf2f(fow[h]), ob = bf2f(fob[0]);
    int t0 = c * 128;
#pragma unroll 1
    for (int blk = 0; blk < 4; ++blk) {
        float ykeep = 0.f;
        float A = 0.f, fwg = 0.f, fbg = 0.f;
#pragma unroll
        for (int tt = 0; tt < 32; ++tt) {
            int t = t0 + blk * 32 + tt;
            if ((tt & 15) == 0) {
                int sidx = (t >> 4) - 1;
                if (sidx < 0) sidx = 0;
                A = Aslow[(b * NSLOW + sidx) * HID + h];
                float g = gslow[(b * NSLOW + sidx) * HID + h];
                fwg = fw * g; fbg = fb * g;
            }
            float xv = bf2f(x[b * T_LEN + t]);
            hv = fmaf(A, hv, fmaf(xv, fwg, fbg));
            float y = hv * wo;
            y += __shfl_xor(y, 1, 64);
            y += __shfl_xor(y, 2, 64);
            y += __shfl_xor(y, 4, 64);
            y += __shfl_xor(y, 8, 64);
            y += __shfl_xor(y, 16, 64);
            if (tt == h) ykeep = y + ob;
        }
        int oidx = b * T_LEN + t0 + blk * 32 + h;
        if (isbf) outb[oidx] = f2bf(ykeep);
        else      outf[oidx] = ykeep;
    }
}

extern "C" void kernel_launch(void* const* d_in, const int* in_sizes, int n_in,
                              void* d_out, int out_size, void* d_ws, size_t ws_size,
                              hipStream_t stream)
{
    ushort_t* cv = (ushort_t*)d_ws;
    const ushort_t* x    = cv + OFF_X;
    const ushort_t* fcw  = cv + OFF_FCW;
    const ushort_t* fcb  = cv + OFF_FCB;
    const ushort_t* wih  = cv + OFF_WIH;
    const ushort_t* whh  = cv + OFF_WHH;
    const ushort_t* bih  = cv + OFF_BIH;
    const ushort_t* bhh  = cv + OFF_BHH;
    const ushort_t* ofw  = cv + OFF_OFW;
    const ushort_t* ofb  = cv + OFF_OFB;
    const ushort_t* finw = cv + OFF_FINW;
    const ushort_t* finb = cv + OFF_FINB;
    const ushort_t* fow  = cv + OFF_FOW;
    const ushort_t* fob  = cv + OFF_FOB;

    float* Aslow = (float*)((char*)d_ws + CONV_PAD_BYTES);  // 8192*32 f32
    float* gslow = Aslow + 8192 * 32;
    float* P     = gslow + 8192 * 32;          // 4*32*NCH
    float* S     = P + 4 * 32 * NCH;
    float* Hpre  = S + 4 * 32 * NCH;
    int*   flag  = (int*)(Hpre + 4 * 32 * NCH);

    Ptrs13 ptrs;
    for (int i = 0; i < 13; ++i) ptrs.p[i] = d_in[i];

    convert_kernel<<<dim3(920), dim3(256), 0, stream>>>(ptrs, flag, cv);
    gru_kernel<<<dim3(256), dim3(256), 0, stream>>>(
        x, fcw, fcb, wih, whh, bih, bhh, ofw, ofb, Aslow, gslow);
    pass1_kernel<<<dim3(128), dim3(256), 0, stream>>>(
        x, Aslow, gslow, finw, finb, P, S);
    scan_kernel<<<dim3(1), dim3(128), 0, stream>>>(P, S, Hpre);
    pass2_kernel<<<dim3(128), dim3(256), 0, stream>>>(
        x, Aslow, gslow, Hpre, finw, finb, fow, fob, flag, d_out);
}